// Round 8
// baseline (291.577 us; speedup 1.0000x reference)
//
#include <hip/hip_runtime.h>
#include <stdint.h>

typedef __attribute__((ext_vector_type(8))) short bf16x8;
typedef __attribute__((ext_vector_type(4))) float f32x4;

__device__ __forceinline__ unsigned short f2bf(float f) {
  union { float f; unsigned u; } v; v.f = f;
  unsigned u = v.u;
  u += 0x7fffu + ((u >> 16) & 1u);
  return (unsigned short)(u >> 16);
}
__device__ __forceinline__ float bfpk_lo(unsigned pk) {
  union { unsigned u; float f; } v; v.u = pk << 16; return v.f;
}
__device__ __forceinline__ float bfpk_hi(unsigned pk) {
  union { unsigned u; float f; } v; v.u = pk & 0xffff0000u; return v.f;
}

// B-fragment swizzle for mfma_f32_16x16x32_bf16:
// element B[k][n] lives at (((k>>5)*16 + (n>>4))*64 + (((k>>3)&3)*16 + (n&15)))*8 + (k&7)
__device__ __forceinline__ int swz_idx(int k, int n) {
  return ((((k >> 5) * 16 + (n >> 4)) * 64) + (((k >> 3) & 3) * 16 + (n & 15))) * 8 + (k & 7);
}

// stage row stride (bf16 elems): 272 -> rows 16B-aligned => A-frag = one ds_read_b128
// (bank-uniform: 8 words/bank exactly). Scalar b16 gamma-writes: banks 8*(m%4)+4q+m/2
// cover all 32 banks <=2-way (free). 272 words==8 mod 32 keeps spread.
#define ST_STRIDE 272

// ---- module-scope scratch; fully rewritten every call ----
__device__ __attribute__((aligned(16))) unsigned short g_Acswz[65536];
__device__ __attribute__((aligned(16))) unsigned short g_Gswz[65536];
__device__ __attribute__((aligned(16))) unsigned short g_W3swz[65536];

// ---------------- fused prep: zero out + build all three swizzled matrices ----------------
// (round-7 verified: G-branch partial sums break the serial FMA/latency chain)
__global__ void prep_all(const float* __restrict__ A, const float* __restrict__ Dw,
                         const float* __restrict__ Ww, float* __restrict__ out) {
  __shared__ float red[256];
  const int b = blockIdx.x;
  const int tid = threadIdx.x;
  out[b * 256 + tid] = 0.f;  // 768*256 == out_size exactly

  if (b < 256) {
    float s = 0.f;
    for (int c = tid; c < 243; c += 256) s += A[b * 243 + c];
    red[tid] = s;
    __syncthreads();
    for (int off = 128; off; off >>= 1) {
      if (tid < off) red[tid] += red[tid + off];
      __syncthreads();
    }
    float rm = red[0] * (1.f / 243.f);
    int k = tid;
    float v = 0.f;
    if (k < 243) {
      int rw = k / 9, j = k - rw * 9;
      int i = rw / 3, c = rw - i * 3;
      int corig = c * 81 + i * 9 + j;
      v = A[b * 243 + corig] - rm;
    }
    g_Acswz[swz_idx(k, b)] = f2bf(v);
  } else if (b < 512) {
    // G = I - A@Dw with 4 independent partial sums (breaks the serial latency chain).
    int f = b - 256, fp = tid;
    const float* Ar = A + f * 243;
    float s0 = 0.f, s1 = 0.f, s2 = 0.f, s3 = 0.f;
    int c = 0;
    for (; c + 4 <= 240; c += 4) {
      s0 += Ar[c + 0] * Dw[(c + 0) * 256 + fp];
      s1 += Ar[c + 1] * Dw[(c + 1) * 256 + fp];
      s2 += Ar[c + 2] * Dw[(c + 2) * 256 + fp];
      s3 += Ar[c + 3] * Dw[(c + 3) * 256 + fp];
    }
    s0 += Ar[240] * Dw[240 * 256 + fp];
    s1 += Ar[241] * Dw[241 * 256 + fp];
    s2 += Ar[242] * Dw[242 * 256 + fp];
    float s = (s0 + s1) + (s2 + s3);
    g_Gswz[swz_idx(fp, f)] = f2bf(((f == fp) ? 1.f : 0.f) - s);
  } else {
    int cc = b - 512, f = tid;
    float v = 0.f;
    if (cc < 243) {
      int rw = cc / 9, j = cc - rw * 9;
      int i = rw / 3, c = rw - i * 3;
      int corig = c * 81 + i * 9 + j;
      v = Ww[corig * 256 + f];
    }
    g_W3swz[swz_idx(f, cc)] = f2bf(v);
  }
}

// ------- GEMM core: acc[t][un] = stage(64x256) @ Bslice + C.
// Round-8 single delta vs round-7: B prefetch deepened 1-ahead -> 2-ahead via a 3-slot
// ring (all indices compile-time: s-loop fully unrolled). Rationale: the s-step was
// vmcnt-latency-paced (~250cyc/step vs ~80cyc MFMA work; slack with 1-ahead = one
// step's MFMA < L2 latency). 2-ahead doubles the slack. Ring regs 48 + acc 64 + linpk
// 32 fits the (256,2) budget with ~100 regs headroom - no spill (r1 lesson checked).
// CMODE 0: C-init = 0; CMODE 1: C-init = unpacked bf16 lin.
template <int CMODE>
__device__ __forceinline__ void run_gemm(const unsigned short* __restrict__ Bsrc,
                                         const unsigned short* stg, int w, int lane,
                                         int m, int q, f32x4 (&acc)[4][4],
                                         const unsigned (&linpk)[4][4][2]) {
  bf16x8 bb[3][4];
#pragma unroll
  for (int p = 0; p < 2; ++p)
#pragma unroll
    for (int un = 0; un < 4; ++un)
      bb[p][un] = *(const bf16x8*)(Bsrc + (((p * 16 + 4 * w + un) * 64 + lane) << 3));
#pragma unroll
  for (int s = 0; s < 8; ++s) {
    if (s < 6) {
#pragma unroll
      for (int un = 0; un < 4; ++un)
        bb[(s + 2) % 3][un] =
            *(const bf16x8*)(Bsrc + ((((s + 2) * 16 + 4 * w + un) * 64 + lane) << 3));
    }
#pragma unroll
    for (int t = 0; t < 4; ++t) {
      bf16x8 afr = *(const bf16x8*)(stg + (t * 16 + m) * ST_STRIDE + s * 32 + q * 8);
#pragma unroll
      for (int un = 0; un < 4; ++un) {
        f32x4 cin;
        if (s == 0) {
          if (CMODE == 1) {
            cin[0] = bfpk_lo(linpk[t][un][0]);
            cin[1] = bfpk_hi(linpk[t][un][0]);
            cin[2] = bfpk_lo(linpk[t][un][1]);
            cin[3] = bfpk_hi(linpk[t][un][1]);
          } else {
            cin = (f32x4){0.f, 0.f, 0.f, 0.f};
          }
        } else {
          cin = acc[t][un];
        }
        acc[t][un] = __builtin_amdgcn_mfma_f32_16x16x32_bf16(afr, bb[s % 3][un], cin, 0, 0, 0);
      }
    }
  }
}

// ---------------- main fused kernel (round-0 structure: best passing) ----------------
// 900 blocks = 4 images * 15*15 tiles of 8x8 positions; 4 waves split 256 features.
// Double-buffered gamma stage -> 1 barrier/iteration. B streamed from L2.
// Session ledger: occupancy axis exhausted (8/16/32 waves/CU all ~225-233us, rounds 0/3);
// bG-register-caching condemned (rounds 4/5/6: deterministic absmax 0.199 with no
// localizable mechanism). Do not revisit either without new evidence.
__global__ __launch_bounds__(256, 2) void lista_fused(
    const float* __restrict__ I, const float* __restrict__ lmb, float* __restrict__ out) {
  __shared__ __attribute__((aligned(16))) unsigned short stage[2][64 * ST_STRIDE];  // 69.6 KB
  __shared__ float img[3][16][16];
  __shared__ float meanv[64];
  __shared__ float outacc[768];

  const int tid = threadIdx.x;
  const int lane = tid & 63;
  const int w = tid >> 6;
  const int m = lane & 15;
  const int q = lane >> 4;

  const int blk = blockIdx.x;
  const int b = blk / 225;
  const int t2 = blk - b * 225;
  const int ty = t2 / 15;
  const int tx = t2 - ty * 15;
  const int py0 = ty * 8, px0 = tx * 8;

  const float* Ib = I + b * (3 * 128 * 128);
  for (int r = tid; r < 768; r += 256) {
    int c = r >> 8;
    int yx = r & 255;
    int y = yx >> 4, x = yx & 15;
    img[c][y][x] = Ib[c * 16384 + (py0 + y) * 128 + (px0 + x)];
    outacc[r] = 0.f;
  }
  if (tid < 64) meanv[tid] = 0.f;
  __syncthreads();

  // ---- build patch stage (k-order k=(i*3+c)*9+j) into stage[0] + per-position means ----
  {
    const int pos = tid & 63;
    const int part = tid >> 6;
    const int y = pos >> 3, x = pos & 7;
    int j = part, c = 0, i = 0;
    float s = 0.f;
    unsigned short* srow = &stage[0][pos * ST_STRIDE];
    for (int kk = 0; kk < 64; ++kk) {
      int k = part + 4 * kk;
      float v = 0.f;
      if (k < 243) { v = img[c][y + i][x + j]; s += v; }
      srow[k] = f2bf(v);
      j += 4;
      if (j >= 9) { j -= 9; if (++c == 3) { c = 0; ++i; } }
    }
    atomicAdd(&meanv[pos], s * (1.f / 243.f));
  }
  __syncthreads();

  f32x4 acc[4][4];
  unsigned linpk[4][4][2];

  // ---- GEMM1: lin = patches @ Ac^T ----
  run_gemm<0>(g_Acswz, stage[0], w, lane, m, q, acc, linpk);

  // pack lin (bf16) + gamma0 = ST(lin, lmb[0]) -> stage[1] (patch stage[0] untouched)
#pragma unroll
  for (int un = 0; un < 4; ++un) {
    int f = 64 * w + un * 16 + m;
    float lam = lmb[f];
#pragma unroll
    for (int t = 0; t < 4; ++t) {
      linpk[t][un][0] = (unsigned)f2bf(acc[t][un][0]) | ((unsigned)f2bf(acc[t][un][1]) << 16);
      linpk[t][un][1] = (unsigned)f2bf(acc[t][un][2]) | ((unsigned)f2bf(acc[t][un][3]) << 16);
#pragma unroll
      for (int r = 0; r < 4; ++r) {
        float x0 = acc[t][un][r];
        float g = x0 - fminf(fmaxf(x0, -lam), lam);  // soft-threshold
        stage[1][(t * 16 + q * 4 + r) * ST_STRIDE + f] = f2bf(g);
      }
    }
  }
  __syncthreads();

  // ---- 11 iterations: gamma <- ST(gamma @ G2 + lin, lmb[kk+1]); buffers alternate ----
  for (int kk = 0; kk < 11; ++kk) {
    const int rb = (kk & 1) ^ 1;  // kk even: read stage[1], write stage[0]
    run_gemm<1>(g_Gswz, stage[rb], w, lane, m, q, acc, linpk);
#pragma unroll
    for (int un = 0; un < 4; ++un) {
      int f = 64 * w + un * 16 + m;
      float lam = lmb[(kk + 1) * 256 + f];
#pragma unroll
      for (int t = 0; t < 4; ++t)
#pragma unroll
        for (int r = 0; r < 4; ++r) {
          float x0 = acc[t][un][r];
          float g = x0 - fminf(fmaxf(x0, -lam), lam);
          stage[rb ^ 1][(t * 16 + q * 4 + r) * ST_STRIDE + f] = f2bf(g);
        }
    }
    __syncthreads();
  }

  // ---- GEMM3: out_cols = gamma_11 (stage[0]) @ W3 (+ mean), fold into outacc ----
  run_gemm<0>(g_W3swz, stage[0], w, lane, m, q, acc, linpk);

#pragma unroll
  for (int un = 0; un < 4; ++un) {
    int cc = 64 * w + un * 16 + m;
    if (cc < 243) {
      int rw = cc / 9, jj = cc - rw * 9;
      int i = rw / 3, c = rw - i * 3;
#pragma unroll
      for (int t = 0; t < 4; ++t)
#pragma unroll
        for (int r = 0; r < 4; ++r) {
          int pos = t * 16 + q * 4 + r;
          int y = (pos >> 3) + i, x = (pos & 7) + jj;
          float val = acc[t][un][r] + meanv[pos];
          atomicAdd(&outacc[c * 256 + y * 16 + x], val);
        }
    }
  }
  __syncthreads();

  float* Ob = out + b * (3 * 128 * 128);
  for (int r = tid; r < 768; r += 256) {
    int c = r >> 8;
    int yx = r & 255;
    int y = yx >> 4, x = yx & 15;
    atomicAdd(&Ob[c * 16384 + (py0 + y) * 128 + (px0 + x)], outacc[r]);
  }
}

// divide by overlap counts
__global__ void div_counts(float* __restrict__ out, int n) {
  int idx = blockIdx.x * 256 + threadIdx.x;
  if (idx >= n) return;
  int x = idx & 127, y = (idx >> 7) & 127;
  int loy = y - 8; if (loy < 0) loy = 0;
  int hiy = y; if (hiy > 119) hiy = 119;
  int lox = x - 8; if (lox < 0) lox = 0;
  int hix = x; if (hix > 119) hix = 119;
  float cnt = (float)((hiy - loy + 1) * (hix - lox + 1));
  out[idx] = out[idx] / cnt;
}

extern "C" void kernel_launch(void* const* d_in, const int* in_sizes, int n_in,
                              void* d_out, int out_size, void* d_ws, size_t ws_size,
                              hipStream_t stream) {
  const float* I = (const float*)d_in[0];
  const float* A = (const float*)d_in[1];
  const float* Dw = (const float*)d_in[2];
  const float* Ww = (const float*)d_in[3];
  const float* lmb = (const float*)d_in[4];
  float* out = (float*)d_out;
  (void)d_ws; (void)ws_size;

  prep_all<<<768, 256, 0, stream>>>(A, Dw, Ww, out);
  lista_fused<<<900, 256, 0, stream>>>(I, lmb, out);
  div_counts<<<768, 256, 0, stream>>>(out, out_size);
}

// Round 9
// 280.193 us; speedup vs baseline: 1.0406x; 1.0406x over previous
//
#include <hip/hip_runtime.h>
#include <stdint.h>

typedef __attribute__((ext_vector_type(8))) short bf16x8;
typedef __attribute__((ext_vector_type(4))) float f32x4;
typedef __attribute__((ext_vector_type(2))) unsigned u32x2;

__device__ __forceinline__ unsigned short f2bf(float f) {
  union { float f; unsigned u; } v; v.f = f;
  unsigned u = v.u;
  u += 0x7fffu + ((u >> 16) & 1u);
  return (unsigned short)(u >> 16);
}
__device__ __forceinline__ float bfpk_lo(unsigned pk) {
  union { unsigned u; float f; } v; v.u = pk << 16; return v.f;
}
__device__ __forceinline__ float bfpk_hi(unsigned pk) {
  union { unsigned u; float f; } v; v.u = pk & 0xffff0000u; return v.f;
}

// B-fragment swizzle for mfma_f32_16x16x32_bf16:
// element B[k][n] lives at (((k>>5)*16 + (n>>4))*64 + (((k>>3)&3)*16 + (n&15)))*8 + (k&7)
__device__ __forceinline__ int swz_idx(int k, int n) {
  return ((((k >> 5) * 16 + (n >> 4)) * 64) + (((k >> 3) & 3) * 16 + (n & 15))) * 8 + (k & 7);
}

// stage row stride (bf16 elems): 272 -> rows 16B-aligned => A-frag = one ds_read_b128
// (bank-uniform: 8 words/bank exactly).
#define ST_STRIDE 272

// ---- module-scope scratch; fully rewritten every call ----
__device__ __attribute__((aligned(16))) unsigned short g_Acswz[65536];
__device__ __attribute__((aligned(16))) unsigned short g_Gswz[65536];
__device__ __attribute__((aligned(16))) unsigned short g_W3swz[65536];

// ---------------- fused prep: zero out + build all three swizzled matrices ----------------
// (round-7 verified: G-branch partial sums break the serial FMA/latency chain)
__global__ void prep_all(const float* __restrict__ A, const float* __restrict__ Dw,
                         const float* __restrict__ Ww, float* __restrict__ out) {
  __shared__ float red[256];
  const int b = blockIdx.x;
  const int tid = threadIdx.x;
  out[b * 256 + tid] = 0.f;  // 768*256 == out_size exactly

  if (b < 256) {
    float s = 0.f;
    for (int c = tid; c < 243; c += 256) s += A[b * 243 + c];
    red[tid] = s;
    __syncthreads();
    for (int off = 128; off; off >>= 1) {
      if (tid < off) red[tid] += red[tid + off];
      __syncthreads();
    }
    float rm = red[0] * (1.f / 243.f);
    int k = tid;
    float v = 0.f;
    if (k < 243) {
      int rw = k / 9, j = k - rw * 9;
      int i = rw / 3, c = rw - i * 3;
      int corig = c * 81 + i * 9 + j;
      v = A[b * 243 + corig] - rm;
    }
    g_Acswz[swz_idx(k, b)] = f2bf(v);
  } else if (b < 512) {
    // G = I - A@Dw with 4 independent partial sums (breaks the serial latency chain).
    int f = b - 256, fp = tid;
    const float* Ar = A + f * 243;
    float s0 = 0.f, s1 = 0.f, s2 = 0.f, s3 = 0.f;
    int c = 0;
    for (; c + 4 <= 240; c += 4) {
      s0 += Ar[c + 0] * Dw[(c + 0) * 256 + fp];
      s1 += Ar[c + 1] * Dw[(c + 1) * 256 + fp];
      s2 += Ar[c + 2] * Dw[(c + 2) * 256 + fp];
      s3 += Ar[c + 3] * Dw[(c + 3) * 256 + fp];
    }
    s0 += Ar[240] * Dw[240 * 256 + fp];
    s1 += Ar[241] * Dw[241 * 256 + fp];
    s2 += Ar[242] * Dw[242 * 256 + fp];
    float s = (s0 + s1) + (s2 + s3);
    g_Gswz[swz_idx(fp, f)] = f2bf(((f == fp) ? 1.f : 0.f) - s);
  } else {
    int cc = b - 512, f = tid;
    float v = 0.f;
    if (cc < 243) {
      int rw = cc / 9, j = cc - rw * 9;
      int i = rw / 3, c = rw - i * 3;
      int corig = c * 81 + i * 9 + j;
      v = Ww[corig * 256 + f];
    }
    g_W3swz[swz_idx(f, cc)] = f2bf(v);
  }
}

// ------- GEMM core: acc[t][un] = stage(64x256) @ Bslice + C.
// Round-9: 2-ahead B prefetch (3-slot ring, all indices compile-time) WITH the register
// room to hold it: linpk evicted to LDS (r8 post-mortem: ring+linpk at the 256-unified
// budget spilled -> FETCH 15->30MB, WRITE 42->63MB; mechanism never tested). Static live
// now ~48 ring + 64 acc(AGPR) + transients, well under the ~192 arch ceiling.
// CMODE 0: C-init = 0; CMODE 1: C-init = unpacked bf16 lin read from LDS (same-thread
// data, written once after GEMM1 - no sync hazard; r5/r6 exonerate lin-in-LDS).
template <int CMODE>
__device__ __forceinline__ void run_gemm(const unsigned short* __restrict__ Bsrc,
                                         const unsigned short* stg, int w, int lane,
                                         int m, int q, f32x4 (&acc)[4][4],
                                         const unsigned* __restrict__ linw) {
  bf16x8 bb[3][4];
#pragma unroll
  for (int p = 0; p < 2; ++p)
#pragma unroll
    for (int un = 0; un < 4; ++un)
      bb[p][un] = *(const bf16x8*)(Bsrc + (((p * 16 + 4 * w + un) * 64 + lane) << 3));
#pragma unroll
  for (int s = 0; s < 8; ++s) {
    if (s < 6) {
#pragma unroll
      for (int un = 0; un < 4; ++un)
        bb[(s + 2) % 3][un] =
            *(const bf16x8*)(Bsrc + ((((s + 2) * 16 + 4 * w + un) * 64 + lane) << 3));
    }
#pragma unroll
    for (int t = 0; t < 4; ++t) {
      bf16x8 afr = *(const bf16x8*)(stg + (t * 16 + m) * ST_STRIDE + s * 32 + q * 8);
#pragma unroll
      for (int un = 0; un < 4; ++un) {
        f32x4 cin;
        if (s == 0) {
          if (CMODE == 1) {
            u32x2 lp = *(const u32x2*)(linw + (t * 4 + un) * 128);
            cin[0] = bfpk_lo(lp[0]);
            cin[1] = bfpk_hi(lp[0]);
            cin[2] = bfpk_lo(lp[1]);
            cin[3] = bfpk_hi(lp[1]);
          } else {
            cin = (f32x4){0.f, 0.f, 0.f, 0.f};
          }
        } else {
          cin = acc[t][un];
        }
        acc[t][un] = __builtin_amdgcn_mfma_f32_16x16x32_bf16(afr, bb[s % 3][un], cin, 0, 0, 0);
      }
    }
  }
}

// ---------------- main fused kernel ----------------
// 900 blocks = 4 images * 15*15 tiles; 4 waves split 256 features (r0 split).
// Round-9 composition (each piece individually vetted):
//  - SINGLE-buffer stage, 2 barriers/iter (r3-verified structure) -> frees 34.8KB LDS
//  - linpk -> 32KB LDS buffer (r5-vs-r6 exonerated as a correctness risk; frees 32 regs)
//  - 2-ahead B prefetch ring (r8 mechanism, now spill-free)
// LDS = 34.8K stage + 32K lin + 3K ibuf + 256B = ~70.9KB -> 2 blocks/CU held.
// Ledger: occupancy axis dead (8/16/32 waves/CU invariant, r0/r3); bG-register caching
// condemned (r4/r5/r6); read-side stage swizzle condemned (r4).
__global__ __launch_bounds__(256, 2) void lista_fused(
    const float* __restrict__ I, const float* __restrict__ lmb, float* __restrict__ out) {
  __shared__ __attribute__((aligned(16))) unsigned short stage[64 * ST_STRIDE];  // 34.8 KB
  __shared__ __attribute__((aligned(16))) unsigned linld[8192];                  // 32 KB lin
  __shared__ __attribute__((aligned(16))) float ibuf[768];  // img (pre-GEMM1) / outacc (post)
  __shared__ float meanv[64];

  const int tid = threadIdx.x;
  const int lane = tid & 63;
  const int w = tid >> 6;
  const int m = lane & 15;
  const int q = lane >> 4;

  const int blk = blockIdx.x;
  const int b = blk / 225;
  const int t2 = blk - b * 225;
  const int ty = t2 / 15;
  const int tx = t2 - ty * 15;
  const int py0 = ty * 8, px0 = tx * 8;

  // per-wave lin base (u32): w*2048 + slot(t*4+un)*128 + lane*2 -- same-thread write/read
  unsigned* linw = linld + w * 2048 + lane * 2;

  const float* Ib = I + b * (3 * 128 * 128);
  for (int r = tid; r < 768; r += 256) {
    int c = r >> 8;
    int yx = r & 255;
    int y = yx >> 4, x = yx & 15;
    ibuf[r] = Ib[c * 16384 + (py0 + y) * 128 + (px0 + x)];  // img[c][y][x]
  }
  if (tid < 64) meanv[tid] = 0.f;
  __syncthreads();

  // ---- build patch stage (k-order k=(i*3+c)*9+j) into stage + per-position means ----
  // (r0's 4-part loop, flat ibuf indexing as verified in r3)
  {
    const int pos = tid & 63;
    const int part = tid >> 6;
    const int y = pos >> 3, x = pos & 7;
    int j = part, c = 0, i = 0;
    float s = 0.f;
    unsigned short* srow = &stage[pos * ST_STRIDE];
    for (int kk = 0; kk < 64; ++kk) {
      int k = part + 4 * kk;
      float v = 0.f;
      if (k < 243) { v = ibuf[c * 256 + (y + i) * 16 + (x + j)]; s += v; }
      srow[k] = f2bf(v);
      j += 4;
      if (j >= 9) { j -= 9; if (++c == 3) { c = 0; ++i; } }
    }
    atomicAdd(&meanv[pos], s * (1.f / 243.f));
  }
  __syncthreads();

  // img no longer needed -> repurpose ibuf as outacc (ordered by later barriers)
  for (int r = tid; r < 768; r += 256) ibuf[r] = 0.f;

  f32x4 acc[4][4];

  // ---- GEMM1: lin = patches @ Ac^T ----
  run_gemm<0>(g_Acswz, stage, w, lane, m, q, acc, nullptr);
  __syncthreads();  // all waves done reading patch stage before gamma0 overwrites it

  // lin (bf16-packed, r0's exact rounding) -> LDS; gamma0 = ST(lin, lmb[0]) -> stage
#pragma unroll
  for (int un = 0; un < 4; ++un) {
    int f = 64 * w + un * 16 + m;
    float lam = lmb[f];
#pragma unroll
    for (int t = 0; t < 4; ++t) {
      unsigned l0 = (unsigned)f2bf(acc[t][un][0]) | ((unsigned)f2bf(acc[t][un][1]) << 16);
      unsigned l1 = (unsigned)f2bf(acc[t][un][2]) | ((unsigned)f2bf(acc[t][un][3]) << 16);
      *(u32x2*)(linw + (t * 4 + un) * 128) = (u32x2){l0, l1};
#pragma unroll
      for (int r = 0; r < 4; ++r) {
        float x0 = acc[t][un][r];
        float g = x0 - fminf(fmaxf(x0, -lam), lam);  // soft-threshold
        stage[(t * 16 + q * 4 + r) * ST_STRIDE + f] = f2bf(g);
      }
    }
  }
  __syncthreads();

  // ---- 11 iterations: gamma <- ST(gamma @ G2 + lin, lmb[kk+1]); single buffer ----
  for (int kk = 0; kk < 11; ++kk) {
    run_gemm<1>(g_Gswz, stage, w, lane, m, q, acc, linw);
    __syncthreads();  // reads complete before in-place overwrite
#pragma unroll
    for (int un = 0; un < 4; ++un) {
      int f = 64 * w + un * 16 + m;
      float lam = lmb[(kk + 1) * 256 + f];
#pragma unroll
      for (int t = 0; t < 4; ++t)
#pragma unroll
        for (int r = 0; r < 4; ++r) {
          float x0 = acc[t][un][r];
          float g = x0 - fminf(fmaxf(x0, -lam), lam);
          stage[(t * 16 + q * 4 + r) * ST_STRIDE + f] = f2bf(g);
        }
    }
    __syncthreads();  // writes visible before next iteration's reads
  }

  // ---- GEMM3: out_cols = gamma_11 @ W3 (+ mean), fold into outacc (ibuf) ----
  run_gemm<0>(g_W3swz, stage, w, lane, m, q, acc, nullptr);

#pragma unroll
  for (int un = 0; un < 4; ++un) {
    int cc = 64 * w + un * 16 + m;
    if (cc < 243) {
      int rw = cc / 9, jj = cc - rw * 9;
      int i = rw / 3, c = rw - i * 3;
#pragma unroll
      for (int t = 0; t < 4; ++t)
#pragma unroll
        for (int r = 0; r < 4; ++r) {
          int pos = t * 16 + q * 4 + r;
          int y = (pos >> 3) + i, x = (pos & 7) + jj;
          float val = acc[t][un][r] + meanv[pos];
          atomicAdd(&ibuf[c * 256 + y * 16 + x], val);
        }
    }
  }
  __syncthreads();

  float* Ob = out + b * (3 * 128 * 128);
  for (int r = tid; r < 768; r += 256) {
    int c = r >> 8;
    int yx = r & 255;
    int y = yx >> 4, x = yx & 15;
    atomicAdd(&Ob[c * 16384 + (py0 + y) * 128 + (px0 + x)], ibuf[r]);
  }
}

// divide by overlap counts
__global__ void div_counts(float* __restrict__ out, int n) {
  int idx = blockIdx.x * 256 + threadIdx.x;
  if (idx >= n) return;
  int x = idx & 127, y = (idx >> 7) & 127;
  int loy = y - 8; if (loy < 0) loy = 0;
  int hiy = y; if (hiy > 119) hiy = 119;
  int lox = x - 8; if (lox < 0) lox = 0;
  int hix = x; if (hix > 119) hix = 119;
  float cnt = (float)((hiy - loy + 1) * (hix - lox + 1));
  out[idx] = out[idx] / cnt;
}

extern "C" void kernel_launch(void* const* d_in, const int* in_sizes, int n_in,
                              void* d_out, int out_size, void* d_ws, size_t ws_size,
                              hipStream_t stream) {
  const float* I = (const float*)d_in[0];
  const float* A = (const float*)d_in[1];
  const float* Dw = (const float*)d_in[2];
  const float* Ww = (const float*)d_in[3];
  const float* lmb = (const float*)d_in[4];
  float* out = (float*)d_out;
  (void)d_ws; (void)ws_size;

  prep_all<<<768, 256, 0, stream>>>(A, Dw, Ww, out);
  lista_fused<<<900, 256, 0, stream>>>(I, lmb, out);
  div_counts<<<768, 256, 0, stream>>>(out, out_size);
}

// Round 11
// 272.653 us; speedup vs baseline: 1.0694x; 1.0277x over previous
//
#include <hip/hip_runtime.h>
#include <stdint.h>

typedef __attribute__((ext_vector_type(8))) short bf16x8;
typedef __attribute__((ext_vector_type(4))) float f32x4;

__device__ __forceinline__ unsigned short f2bf(float f) {
  union { float f; unsigned u; } v; v.f = f;
  unsigned u = v.u;
  u += 0x7fffu + ((u >> 16) & 1u);
  return (unsigned short)(u >> 16);
}
__device__ __forceinline__ float bfpk_lo(unsigned pk) {
  union { unsigned u; float f; } v; v.u = pk << 16; return v.f;
}
__device__ __forceinline__ float bfpk_hi(unsigned pk) {
  union { unsigned u; float f; } v; v.u = pk & 0xffff0000u; return v.f;
}

// B-fragment swizzle for mfma_f32_16x16x32_bf16:
// element B[k][n] lives at (((k>>5)*16 + (n>>4))*64 + (((k>>3)&3)*16 + (n&15)))*8 + (k&7)
__device__ __forceinline__ int swz_idx(int k, int n) {
  return ((((k >> 5) * 16 + (n >> 4)) * 64) + (((k >> 3) & 3) * 16 + (n & 15))) * 8 + (k & 7);
}

// stage row stride (bf16 elems): 272 -> rows 16B-aligned => A-frag = one ds_read_b128
// (bank-uniform: 8 words/bank exactly).
#define ST_STRIDE 272

// ---- module-scope scratch; fully rewritten every call ----
__device__ __attribute__((aligned(16))) unsigned short g_Acswz[65536];
__device__ __attribute__((aligned(16))) unsigned short g_Gswz[65536];
__device__ __attribute__((aligned(16))) unsigned short g_W3swz[65536];

// ---------------- fused prep: zero out + build all three swizzled matrices ----------------
// (round-7 verified: G-branch partial sums break the serial FMA/latency chain)
__global__ void prep_all(const float* __restrict__ A, const float* __restrict__ Dw,
                         const float* __restrict__ Ww, float* __restrict__ out) {
  __shared__ float red[256];
  const int b = blockIdx.x;
  const int tid = threadIdx.x;
  out[b * 256 + tid] = 0.f;  // 768*256 == out_size exactly

  if (b < 256) {
    float s = 0.f;
    for (int c = tid; c < 243; c += 256) s += A[b * 243 + c];
    red[tid] = s;
    __syncthreads();
    for (int off = 128; off; off >>= 1) {
      if (tid < off) red[tid] += red[tid + off];
      __syncthreads();
    }
    float rm = red[0] * (1.f / 243.f);
    int k = tid;
    float v = 0.f;
    if (k < 243) {
      int rw = k / 9, j = k - rw * 9;
      int i = rw / 3, c = rw - i * 3;
      int corig = c * 81 + i * 9 + j;
      v = A[b * 243 + corig] - rm;
    }
    g_Acswz[swz_idx(k, b)] = f2bf(v);
  } else if (b < 512) {
    // G = I - A@Dw with 4 independent partial sums (breaks the serial latency chain).
    int f = b - 256, fp = tid;
    const float* Ar = A + f * 243;
    float s0 = 0.f, s1 = 0.f, s2 = 0.f, s3 = 0.f;
    int c = 0;
    for (; c + 4 <= 240; c += 4) {
      s0 += Ar[c + 0] * Dw[(c + 0) * 256 + fp];
      s1 += Ar[c + 1] * Dw[(c + 1) * 256 + fp];
      s2 += Ar[c + 2] * Dw[(c + 2) * 256 + fp];
      s3 += Ar[c + 3] * Dw[(c + 3) * 256 + fp];
    }
    s0 += Ar[240] * Dw[240 * 256 + fp];
    s1 += Ar[241] * Dw[241 * 256 + fp];
    s2 += Ar[242] * Dw[242 * 256 + fp];
    float s = (s0 + s1) + (s2 + s3);
    g_Gswz[swz_idx(fp, f)] = f2bf(((f == fp) ? 1.f : 0.f) - s);
  } else {
    int cc = b - 512, f = tid;
    float v = 0.f;
    if (cc < 243) {
      int rw = cc / 9, j = cc - rw * 9;
      int i = rw / 3, c = rw - i * 3;
      int corig = c * 81 + i * 9 + j;
      v = Ww[corig * 256 + f];
    }
    g_W3swz[swz_idx(f, cc)] = f2bf(v);
  }
}

// ------- GEMM core: acc[t][un] = stage(64x256) @ Bslice + C. B streamed (1-ahead prefetch).
// CMODE 0: C-init = 0; CMODE 1: C-init = unpacked bf16 lin.   (verbatim round-7)
template <int CMODE>
__device__ __forceinline__ void run_gemm(const unsigned short* __restrict__ Bsrc,
                                         const unsigned short* stg, int w, int lane,
                                         int m, int q, f32x4 (&acc)[4][4],
                                         const unsigned (&linpk)[4][4][2]) {
  bf16x8 bcur[4];
#pragma unroll
  for (int un = 0; un < 4; ++un)
    bcur[un] = *(const bf16x8*)(Bsrc + (((4 * w + un) * 64 + lane) << 3));
#pragma unroll
  for (int s = 0; s < 8; ++s) {
    bf16x8 bnext[4];
    if (s < 7) {
#pragma unroll
      for (int un = 0; un < 4; ++un)
        bnext[un] = *(const bf16x8*)(Bsrc + ((((s + 1) * 16 + 4 * w + un) * 64 + lane) << 3));
    }
#pragma unroll
    for (int t = 0; t < 4; ++t) {
      bf16x8 afr = *(const bf16x8*)(stg + (t * 16 + m) * ST_STRIDE + s * 32 + q * 8);
#pragma unroll
      for (int un = 0; un < 4; ++un) {
        f32x4 cin;
        if (s == 0) {
          if (CMODE == 1) {
            cin[0] = bfpk_lo(linpk[t][un][0]);
            cin[1] = bfpk_hi(linpk[t][un][0]);
            cin[2] = bfpk_lo(linpk[t][un][1]);
            cin[3] = bfpk_hi(linpk[t][un][1]);
          } else {
            cin = (f32x4){0.f, 0.f, 0.f, 0.f};
          }
        } else {
          cin = acc[t][un];
        }
        acc[t][un] = __builtin_amdgcn_mfma_f32_16x16x32_bf16(afr, bcur[un], cin, 0, 0, 0);
      }
    }
    if (s < 7) {
#pragma unroll
      for (int un = 0; un < 4; ++un) bcur[un] = bnext[un];
    }
  }
}

// ---------------- main fused kernel (round-7 structure: banked best, 222us) ----------------
// Round-11 single delta vs r7: per-iteration lmb loads hoisted above run_gemm (hides
// ~300cyc L2 latency under the GEMM, 12x per block). f2bf epilogue kept verbatim.
// Ledger: occupancy axis dead (8/16/32 waves/CU, r0/r3); B-prefetch depth dead (r9);
// single-buffer costs +9us vs dbuf (r9 vs r7); bG-register caching condemned (r4/5/6);
// read-side stage swizzle condemned (r4); inline-asm cvt_pk condemned in this kernel
// family (r10: absmax 3e35; r5/r6 shared it; mechanism not localized - do NOT reuse).
__global__ __launch_bounds__(256, 2) void lista_fused(
    const float* __restrict__ I, const float* __restrict__ lmb, float* __restrict__ out) {
  __shared__ __attribute__((aligned(16))) unsigned short stage[2][64 * ST_STRIDE];  // 69.6 KB
  __shared__ float img[3][16][16];
  __shared__ float meanv[64];
  __shared__ float outacc[768];

  const int tid = threadIdx.x;
  const int lane = tid & 63;
  const int w = tid >> 6;
  const int m = lane & 15;
  const int q = lane >> 4;

  const int blk = blockIdx.x;
  const int b = blk / 225;
  const int t2 = blk - b * 225;
  const int ty = t2 / 15;
  const int tx = t2 - ty * 15;
  const int py0 = ty * 8, px0 = tx * 8;

  const float* Ib = I + b * (3 * 128 * 128);
  for (int r = tid; r < 768; r += 256) {
    int c = r >> 8;
    int yx = r & 255;
    int y = yx >> 4, x = yx & 15;
    img[c][y][x] = Ib[c * 16384 + (py0 + y) * 128 + (px0 + x)];
    outacc[r] = 0.f;
  }
  if (tid < 64) meanv[tid] = 0.f;
  __syncthreads();

  // ---- build patch stage (k-order k=(i*3+c)*9+j) into stage[0] + per-position means ----
  {
    const int pos = tid & 63;
    const int part = tid >> 6;
    const int y = pos >> 3, x = pos & 7;
    int j = part, c = 0, i = 0;
    float s = 0.f;
    unsigned short* srow = &stage[0][pos * ST_STRIDE];
    for (int kk = 0; kk < 64; ++kk) {
      int k = part + 4 * kk;
      float v = 0.f;
      if (k < 243) { v = img[c][y + i][x + j]; s += v; }
      srow[k] = f2bf(v);
      j += 4;
      if (j >= 9) { j -= 9; if (++c == 3) { c = 0; ++i; } }
    }
    atomicAdd(&meanv[pos], s * (1.f / 243.f));
  }
  __syncthreads();

  f32x4 acc[4][4];
  unsigned linpk[4][4][2];

  // lmb row 0 prefetched before GEMM1 (completes under the GEMM)
  float lam0[4];
#pragma unroll
  for (int un = 0; un < 4; ++un) lam0[un] = lmb[64 * w + un * 16 + m];

  // ---- GEMM1: lin = patches @ Ac^T ----
  run_gemm<0>(g_Acswz, stage[0], w, lane, m, q, acc, linpk);

  // pack lin (bf16) + gamma0 = ST(lin, lmb[0]) -> stage[1] (patch stage[0] untouched)
#pragma unroll
  for (int un = 0; un < 4; ++un) {
    int f = 64 * w + un * 16 + m;
    float lam = lam0[un];
#pragma unroll
    for (int t = 0; t < 4; ++t) {
      linpk[t][un][0] = (unsigned)f2bf(acc[t][un][0]) | ((unsigned)f2bf(acc[t][un][1]) << 16);
      linpk[t][un][1] = (unsigned)f2bf(acc[t][un][2]) | ((unsigned)f2bf(acc[t][un][3]) << 16);
#pragma unroll
      for (int r = 0; r < 4; ++r) {
        float x0 = acc[t][un][r];
        float g = x0 - fminf(fmaxf(x0, -lam), lam);  // soft-threshold
        stage[1][(t * 16 + q * 4 + r) * ST_STRIDE + f] = f2bf(g);
      }
    }
  }
  __syncthreads();

  // ---- 11 iterations: gamma <- ST(gamma @ G2 + lin, lmb[kk+1]); buffers alternate ----
  for (int kk = 0; kk < 11; ++kk) {
    const int rb = (kk & 1) ^ 1;  // kk even: read stage[1], write stage[0]
    float lamv[4];
#pragma unroll
    for (int un = 0; un < 4; ++un) lamv[un] = lmb[(kk + 1) * 256 + 64 * w + un * 16 + m];
    run_gemm<1>(g_Gswz, stage[rb], w, lane, m, q, acc, linpk);
#pragma unroll
    for (int un = 0; un < 4; ++un) {
      int f = 64 * w + un * 16 + m;
      float lam = lamv[un];
#pragma unroll
      for (int t = 0; t < 4; ++t)
#pragma unroll
        for (int r = 0; r < 4; ++r) {
          float x0 = acc[t][un][r];
          float g = x0 - fminf(fmaxf(x0, -lam), lam);
          stage[rb ^ 1][(t * 16 + q * 4 + r) * ST_STRIDE + f] = f2bf(g);
        }
    }
    __syncthreads();
  }

  // ---- GEMM3: out_cols = gamma_11 (stage[0]) @ W3 (+ mean), fold into outacc ----
  run_gemm<0>(g_W3swz, stage[0], w, lane, m, q, acc, linpk);

#pragma unroll
  for (int un = 0; un < 4; ++un) {
    int cc = 64 * w + un * 16 + m;
    if (cc < 243) {
      int rw = cc / 9, jj = cc - rw * 9;
      int i = rw / 3, c = rw - i * 3;
#pragma unroll
      for (int t = 0; t < 4; ++t)
#pragma unroll
        for (int r = 0; r < 4; ++r) {
          int pos = t * 16 + q * 4 + r;
          int y = (pos >> 3) + i, x = (pos & 7) + jj;
          float val = acc[t][un][r] + meanv[pos];
          atomicAdd(&outacc[c * 256 + y * 16 + x], val);
        }
    }
  }
  __syncthreads();

  float* Ob = out + b * (3 * 128 * 128);
  for (int r = tid; r < 768; r += 256) {
    int c = r >> 8;
    int yx = r & 255;
    int y = yx >> 4, x = yx & 15;
    atomicAdd(&Ob[c * 16384 + (py0 + y) * 128 + (px0 + x)], outacc[r]);
  }
}

// divide by overlap counts
__global__ void div_counts(float* __restrict__ out, int n) {
  int idx = blockIdx.x * 256 + threadIdx.x;
  if (idx >= n) return;
  int x = idx & 127, y = (idx >> 7) & 127;
  int loy = y - 8; if (loy < 0) loy = 0;
  int hiy = y; if (hiy > 119) hiy = 119;
  int lox = x - 8; if (lox < 0) lox = 0;
  int hix = x; if (hix > 119) hix = 119;
  float cnt = (float)((hiy - loy + 1) * (hix - lox + 1));
  out[idx] = out[idx] / cnt;
}

extern "C" void kernel_launch(void* const* d_in, const int* in_sizes, int n_in,
                              void* d_out, int out_size, void* d_ws, size_t ws_size,
                              hipStream_t stream) {
  const float* I = (const float*)d_in[0];
  const float* A = (const float*)d_in[1];
  const float* Dw = (const float*)d_in[2];
  const float* Ww = (const float*)d_in[3];
  const float* lmb = (const float*)d_in[4];
  float* out = (float*)d_out;
  (void)d_ws; (void)ws_size;

  prep_all<<<768, 256, 0, stream>>>(A, Dw, Ww, out);
  lista_fused<<<900, 256, 0, stream>>>(I, lmb, out);
  div_counts<<<768, 256, 0, stream>>>(out, out_size);
}

// Round 12
// 268.404 us; speedup vs baseline: 1.0863x; 1.0158x over previous
//
#include <hip/hip_runtime.h>
#include <stdint.h>

typedef __attribute__((ext_vector_type(8))) short bf16x8;
typedef __attribute__((ext_vector_type(4))) float f32x4;

__device__ __forceinline__ unsigned short f2bf(float f) {
  union { float f; unsigned u; } v; v.f = f;
  unsigned u = v.u;
  u += 0x7fffu + ((u >> 16) & 1u);
  return (unsigned short)(u >> 16);
}
// Compiler-native bf16 convert (RTNE, bit-identical to f2bf): fptrunc lowers to
// v_cvt_pk_bf16_f32 on gfx950 through the compiler's own scheduler — NOT inline asm
// (inline-asm cvt_pk is condemned in this kernel family: r4/5/6/10 failures).
__device__ __forceinline__ unsigned short f2bf_hw(float f) {
  __bf16 b = (__bf16)f;
  return __builtin_bit_cast(unsigned short, b);
}
__device__ __forceinline__ float bfpk_lo(unsigned pk) {
  union { unsigned u; float f; } v; v.u = pk << 16; return v.f;
}
__device__ __forceinline__ float bfpk_hi(unsigned pk) {
  union { unsigned u; float f; } v; v.u = pk & 0xffff0000u; return v.f;
}

// B-fragment swizzle for mfma_f32_16x16x32_bf16:
// element B[k][n] lives at (((k>>5)*16 + (n>>4))*64 + (((k>>3)&3)*16 + (n&15)))*8 + (k&7)
__device__ __forceinline__ int swz_idx(int k, int n) {
  return ((((k >> 5) * 16 + (n >> 4)) * 64) + (((k >> 3) & 3) * 16 + (n & 15))) * 8 + (k & 7);
}

// stage row stride (bf16 elems): 272 -> rows 16B-aligned => A-frag = one ds_read_b128
// (bank-uniform: 8 words/bank exactly).
#define ST_STRIDE 272

// ---- module-scope scratch; fully rewritten every call ----
__device__ __attribute__((aligned(16))) unsigned short g_Acswz[65536];
__device__ __attribute__((aligned(16))) unsigned short g_Gswz[65536];
__device__ __attribute__((aligned(16))) unsigned short g_W3swz[65536];

// ---------------- fused prep: zero out + build all three swizzled matrices ----------------
// (round-7 verified: G-branch partial sums break the serial FMA/latency chain)
__global__ void prep_all(const float* __restrict__ A, const float* __restrict__ Dw,
                         const float* __restrict__ Ww, float* __restrict__ out) {
  __shared__ float red[256];
  const int b = blockIdx.x;
  const int tid = threadIdx.x;
  out[b * 256 + tid] = 0.f;  // 768*256 == out_size exactly

  if (b < 256) {
    float s = 0.f;
    for (int c = tid; c < 243; c += 256) s += A[b * 243 + c];
    red[tid] = s;
    __syncthreads();
    for (int off = 128; off; off >>= 1) {
      if (tid < off) red[tid] += red[tid + off];
      __syncthreads();
    }
    float rm = red[0] * (1.f / 243.f);
    int k = tid;
    float v = 0.f;
    if (k < 243) {
      int rw = k / 9, j = k - rw * 9;
      int i = rw / 3, c = rw - i * 3;
      int corig = c * 81 + i * 9 + j;
      v = A[b * 243 + corig] - rm;
    }
    g_Acswz[swz_idx(k, b)] = f2bf(v);
  } else if (b < 512) {
    // G = I - A@Dw with 4 independent partial sums (breaks the serial latency chain).
    int f = b - 256, fp = tid;
    const float* Ar = A + f * 243;
    float s0 = 0.f, s1 = 0.f, s2 = 0.f, s3 = 0.f;
    int c = 0;
    for (; c + 4 <= 240; c += 4) {
      s0 += Ar[c + 0] * Dw[(c + 0) * 256 + fp];
      s1 += Ar[c + 1] * Dw[(c + 1) * 256 + fp];
      s2 += Ar[c + 2] * Dw[(c + 2) * 256 + fp];
      s3 += Ar[c + 3] * Dw[(c + 3) * 256 + fp];
    }
    s0 += Ar[240] * Dw[240 * 256 + fp];
    s1 += Ar[241] * Dw[241 * 256 + fp];
    s2 += Ar[242] * Dw[242 * 256 + fp];
    float s = (s0 + s1) + (s2 + s3);
    g_Gswz[swz_idx(fp, f)] = f2bf(((f == fp) ? 1.f : 0.f) - s);
  } else {
    int cc = b - 512, f = tid;
    float v = 0.f;
    if (cc < 243) {
      int rw = cc / 9, j = cc - rw * 9;
      int i = rw / 3, c = rw - i * 3;
      int corig = c * 81 + i * 9 + j;
      v = Ww[corig * 256 + f];
    }
    g_W3swz[swz_idx(f, cc)] = f2bf(v);
  }
}

// ------- GEMM core: acc[t][un] = stage(64x256) @ Bslice + C. B streamed (1-ahead prefetch).
// CMODE 0: C-init = 0; CMODE 1: C-init = unpacked bf16 lin.   (verbatim round-7)
template <int CMODE>
__device__ __forceinline__ void run_gemm(const unsigned short* __restrict__ Bsrc,
                                         const unsigned short* stg, int w, int lane,
                                         int m, int q, f32x4 (&acc)[4][4],
                                         const unsigned (&linpk)[4][4][2]) {
  bf16x8 bcur[4];
#pragma unroll
  for (int un = 0; un < 4; ++un)
    bcur[un] = *(const bf16x8*)(Bsrc + (((4 * w + un) * 64 + lane) << 3));
#pragma unroll
  for (int s = 0; s < 8; ++s) {
    bf16x8 bnext[4];
    if (s < 7) {
#pragma unroll
      for (int un = 0; un < 4; ++un)
        bnext[un] = *(const bf16x8*)(Bsrc + ((((s + 1) * 16 + 4 * w + un) * 64 + lane) << 3));
    }
#pragma unroll
    for (int t = 0; t < 4; ++t) {
      bf16x8 afr = *(const bf16x8*)(stg + (t * 16 + m) * ST_STRIDE + s * 32 + q * 8);
#pragma unroll
      for (int un = 0; un < 4; ++un) {
        f32x4 cin;
        if (s == 0) {
          if (CMODE == 1) {
            cin[0] = bfpk_lo(linpk[t][un][0]);
            cin[1] = bfpk_hi(linpk[t][un][0]);
            cin[2] = bfpk_lo(linpk[t][un][1]);
            cin[3] = bfpk_hi(linpk[t][un][1]);
          } else {
            cin = (f32x4){0.f, 0.f, 0.f, 0.f};
          }
        } else {
          cin = acc[t][un];
        }
        acc[t][un] = __builtin_amdgcn_mfma_f32_16x16x32_bf16(afr, bcur[un], cin, 0, 0, 0);
      }
    }
    if (s < 7) {
#pragma unroll
      for (int un = 0; un < 4; ++un) bcur[un] = bnext[un];
    }
  }
}

// ---------------- main fused kernel (round-11 structure: banked best, 272.65us total) -------
// Round-12 single delta vs r11: epilogue conversions use f2bf_hw (compiler-native
// fptrunc->v_cvt_pk_bf16_f32, ~1 op vs f2bf's ~4-5) at the three hot sites (linpk pack,
// gamma0, iteration gamma). Same RTNE bits; staging/prep keep f2bf (cold paths).
// Ledger: occupancy axis dead (8/16/32 waves/CU, r0/r3); B-prefetch depth dead (r9);
// single-buffer costs +9us vs dbuf (r9 vs r7); bG-register caching condemned (r4/5/6);
// read-side stage swizzle condemned (r4); INLINE-ASM cvt_pk condemned (r10: 3e35).
__global__ __launch_bounds__(256, 2) void lista_fused(
    const float* __restrict__ I, const float* __restrict__ lmb, float* __restrict__ out) {
  __shared__ __attribute__((aligned(16))) unsigned short stage[2][64 * ST_STRIDE];  // 69.6 KB
  __shared__ float img[3][16][16];
  __shared__ float meanv[64];
  __shared__ float outacc[768];

  const int tid = threadIdx.x;
  const int lane = tid & 63;
  const int w = tid >> 6;
  const int m = lane & 15;
  const int q = lane >> 4;

  const int blk = blockIdx.x;
  const int b = blk / 225;
  const int t2 = blk - b * 225;
  const int ty = t2 / 15;
  const int tx = t2 - ty * 15;
  const int py0 = ty * 8, px0 = tx * 8;

  const float* Ib = I + b * (3 * 128 * 128);
  for (int r = tid; r < 768; r += 256) {
    int c = r >> 8;
    int yx = r & 255;
    int y = yx >> 4, x = yx & 15;
    img[c][y][x] = Ib[c * 16384 + (py0 + y) * 128 + (px0 + x)];
    outacc[r] = 0.f;
  }
  if (tid < 64) meanv[tid] = 0.f;
  __syncthreads();

  // ---- build patch stage (k-order k=(i*3+c)*9+j) into stage[0] + per-position means ----
  {
    const int pos = tid & 63;
    const int part = tid >> 6;
    const int y = pos >> 3, x = pos & 7;
    int j = part, c = 0, i = 0;
    float s = 0.f;
    unsigned short* srow = &stage[0][pos * ST_STRIDE];
    for (int kk = 0; kk < 64; ++kk) {
      int k = part + 4 * kk;
      float v = 0.f;
      if (k < 243) { v = img[c][y + i][x + j]; s += v; }
      srow[k] = f2bf(v);
      j += 4;
      if (j >= 9) { j -= 9; if (++c == 3) { c = 0; ++i; } }
    }
    atomicAdd(&meanv[pos], s * (1.f / 243.f));
  }
  __syncthreads();

  f32x4 acc[4][4];
  unsigned linpk[4][4][2];

  // lmb row 0 prefetched before GEMM1 (completes under the GEMM)
  float lam0[4];
#pragma unroll
  for (int un = 0; un < 4; ++un) lam0[un] = lmb[64 * w + un * 16 + m];

  // ---- GEMM1: lin = patches @ Ac^T ----
  run_gemm<0>(g_Acswz, stage[0], w, lane, m, q, acc, linpk);

  // pack lin (bf16) + gamma0 = ST(lin, lmb[0]) -> stage[1] (patch stage[0] untouched)
#pragma unroll
  for (int un = 0; un < 4; ++un) {
    int f = 64 * w + un * 16 + m;
    float lam = lam0[un];
#pragma unroll
    for (int t = 0; t < 4; ++t) {
      linpk[t][un][0] = (unsigned)f2bf_hw(acc[t][un][0]) | ((unsigned)f2bf_hw(acc[t][un][1]) << 16);
      linpk[t][un][1] = (unsigned)f2bf_hw(acc[t][un][2]) | ((unsigned)f2bf_hw(acc[t][un][3]) << 16);
#pragma unroll
      for (int r = 0; r < 4; ++r) {
        float x0 = acc[t][un][r];
        float g = x0 - fminf(fmaxf(x0, -lam), lam);  // soft-threshold
        stage[1][(t * 16 + q * 4 + r) * ST_STRIDE + f] = f2bf_hw(g);
      }
    }
  }
  __syncthreads();

  // ---- 11 iterations: gamma <- ST(gamma @ G2 + lin, lmb[kk+1]); buffers alternate ----
  for (int kk = 0; kk < 11; ++kk) {
    const int rb = (kk & 1) ^ 1;  // kk even: read stage[1], write stage[0]
    float lamv[4];
#pragma unroll
    for (int un = 0; un < 4; ++un) lamv[un] = lmb[(kk + 1) * 256 + 64 * w + un * 16 + m];
    run_gemm<1>(g_Gswz, stage[rb], w, lane, m, q, acc, linpk);
#pragma unroll
    for (int un = 0; un < 4; ++un) {
      int f = 64 * w + un * 16 + m;
      float lam = lamv[un];
#pragma unroll
      for (int t = 0; t < 4; ++t)
#pragma unroll
        for (int r = 0; r < 4; ++r) {
          float x0 = acc[t][un][r];
          float g = x0 - fminf(fmaxf(x0, -lam), lam);
          stage[rb ^ 1][(t * 16 + q * 4 + r) * ST_STRIDE + f] = f2bf_hw(g);
        }
    }
    __syncthreads();
  }

  // ---- GEMM3: out_cols = gamma_11 (stage[0]) @ W3 (+ mean), fold into outacc ----
  run_gemm<0>(g_W3swz, stage[0], w, lane, m, q, acc, linpk);

#pragma unroll
  for (int un = 0; un < 4; ++un) {
    int cc = 64 * w + un * 16 + m;
    if (cc < 243) {
      int rw = cc / 9, jj = cc - rw * 9;
      int i = rw / 3, c = rw - i * 3;
#pragma unroll
      for (int t = 0; t < 4; ++t)
#pragma unroll
        for (int r = 0; r < 4; ++r) {
          int pos = t * 16 + q * 4 + r;
          int y = (pos >> 3) + i, x = (pos & 7) + jj;
          float val = acc[t][un][r] + meanv[pos];
          atomicAdd(&outacc[c * 256 + y * 16 + x], val);
        }
    }
  }
  __syncthreads();

  float* Ob = out + b * (3 * 128 * 128);
  for (int r = tid; r < 768; r += 256) {
    int c = r >> 8;
    int yx = r & 255;
    int y = yx >> 4, x = yx & 15;
    atomicAdd(&Ob[c * 16384 + (py0 + y) * 128 + (px0 + x)], outacc[r]);
  }
}

// divide by overlap counts
__global__ void div_counts(float* __restrict__ out, int n) {
  int idx = blockIdx.x * 256 + threadIdx.x;
  if (idx >= n) return;
  int x = idx & 127, y = (idx >> 7) & 127;
  int loy = y - 8; if (loy < 0) loy = 0;
  int hiy = y; if (hiy > 119) hiy = 119;
  int lox = x - 8; if (lox < 0) lox = 0;
  int hix = x; if (hix > 119) hix = 119;
  float cnt = (float)((hiy - loy + 1) * (hix - lox + 1));
  out[idx] = out[idx] / cnt;
}

extern "C" void kernel_launch(void* const* d_in, const int* in_sizes, int n_in,
                              void* d_out, int out_size, void* d_ws, size_t ws_size,
                              hipStream_t stream) {
  const float* I = (const float*)d_in[0];
  const float* A = (const float*)d_in[1];
  const float* Dw = (const float*)d_in[2];
  const float* Ww = (const float*)d_in[3];
  const float* lmb = (const float*)d_in[4];
  float* out = (float*)d_out;
  (void)d_ws; (void)ws_size;

  prep_all<<<768, 256, 0, stream>>>(A, Dw, Ww, out);
  lista_fused<<<900, 256, 0, stream>>>(I, lmb, out);
  div_counts<<<768, 256, 0, stream>>>(out, out_size);
}